// Round 7
// baseline (562.513 us; speedup 1.0000x reference)
//
#include <hip/hip_runtime.h>
#include <math.h>

#define N_NODES 4096
#define HIDN 128
#define MAXNZ 128

typedef float v4f __attribute__((ext_vector_type(4)));
typedef _Float16 h2 __attribute__((ext_vector_type(2)));
typedef _Float16 h8 __attribute__((ext_vector_type(8)));

__device__ __forceinline__ float fsig(float x) { return 1.0f / (1.0f + __expf(-x)); }
__device__ __forceinline__ float ftanh_(float x) { return 1.0f - 2.0f / (__expf(2.0f * x) + 1.0f); }

// ---------------------------------------------------------------------------
// K1 fused: blocks [0,2048) = A-scan (8 rows each); [2048,2176) = conv+z.
// Scan v4: hit indices buffered in LDS (ds_write, wave-local, no barrier),
// ONE coalesced global store per row at the end; all 16 row-loads issued
// up front (16 KB in flight per wave).
// z layout: z4[b][chunk:8][cell:128][gate:4][s:16].
// ---------------------------------------------------------------------------
__global__ __launch_bounds__(512) void k_scan_conv(
        const float* __restrict__ A, float* __restrict__ d_inv,
        int* __restrict__ cnt, int* __restrict__ idx,
        const float* __restrict__ x, const float* __restrict__ conv_w,
        const float* __restrict__ conv_b, const float* __restrict__ w_ih,
        const float* __restrict__ b_ih, const float* __restrict__ b_hh,
        float* __restrict__ z4) {
    if (blockIdx.x < 2048) {
        // ---- A-scan: 8 waves = 8 rows per block ----
        const int wid = threadIdx.x >> 6;
        const int lane = threadIdx.x & 63;
        const int r = blockIdx.x * 8 + wid;
        const v4f* row = (const v4f*)(A + (size_t)r * N_NODES);
        __shared__ int sidx[8][MAXNZ];
        const unsigned long long below = (1ull << lane) - 1ull;
        int cbase = 0;
        v4f v[16];
        #pragma unroll
        for (int j = 0; j < 16; ++j)
            v[j] = row[j * 64 + lane];
#define PROC1(c, col)                                                         \
        {                                                                     \
            bool nz = ((c) != 0.0f);                                          \
            unsigned long long mm = __ballot(nz);                             \
            if (mm) {                                                         \
                if (nz) {                                                     \
                    int p_ = cbase + __popcll(mm & below);                    \
                    if (p_ < MAXNZ) sidx[wid][p_] = (col);                    \
                }                                                             \
                cbase += __popcll(mm);                                        \
            }                                                                 \
        }
        #pragma unroll
        for (int j = 0; j < 16; ++j) {
            int col0 = (j * 64 + lane) * 4;
            PROC1(v[j].x, col0 + 0);
            PROC1(v[j].y, col0 + 1);
            PROC1(v[j].z, col0 + 2);
            PROC1(v[j].w, col0 + 3);
        }
#undef PROC1
        int cnt_r = (cbase < MAXNZ) ? cbase : MAXNZ;
        // wave-local: compiler inserts lgkmcnt wait before the LDS read
        for (int k = lane; k < cnt_r; k += 64)
            idx[r * MAXNZ + k] = sidx[wid][k];
        if (lane == 0) {
            cnt[r] = cnt_r;
            d_inv[r] = rsqrtf((float)(cbase + 1));
        }
    } else {
        // ---- conv1d + z precompute: 4 timesteps per block ----
        const int cb = blockIdx.x - 2048;
        const int b = cb >> 5;
        const int t0 = (cb & 31) * 4;
        const int tsub = threadIdx.x >> 7;
        const int h = threadIdx.x & 127;
        const int t = t0 + tsub;                   // timestep 0..127
        __shared__ __align__(16) float dyn_lds[4][HIDN];
        const float* xb = x + ((size_t)b * N_NODES + (N_NODES - HIDN)) * HIDN;
        const float* w = conv_w + (size_t)t * HIDN * 3;
        float a0 = conv_b[t], a1 = 0.0f, a2 = 0.0f, a3 = 0.0f;
        #pragma unroll 4
        for (int i = 0; i < HIDN; i += 4) {
            const float* xr0 = xb + (size_t)i * HIDN;
            #pragma unroll
            for (int s = 0; s < 4; ++s) {
                const float* xr = xr0 + s * HIDN;
                float w0 = w[(i + s) * 3 + 0], w1 = w[(i + s) * 3 + 1], w2 = w[(i + s) * 3 + 2];
                float left  = (h > 0)   ? xr[h - 1] : 0.0f;
                float mid   = xr[h];
                float right = (h < 127) ? xr[h + 1] : 0.0f;
                if (s == 0)      a0 += left * w0 + mid * w1 + right * w2;
                else if (s == 1) a1 += left * w0 + mid * w1 + right * w2;
                else if (s == 2) a2 += left * w0 + mid * w1 + right * w2;
                else             a3 += left * w0 + mid * w1 + right * w2;
            }
        }
        dyn_lds[tsub][h] = (a0 + a1) + (a2 + a3);
        __syncthreads();
        const float4* dyn4 = (const float4*)dyn_lds[tsub];
        const int ch = t >> 4, si = t & 15;
        for (int qg = 0; qg < 4; ++qg) {
            int u = h + 128 * qg;                  // gate qg, cell h
            const float4* wr = (const float4*)(w_ih + (size_t)u * HIDN);
            float za = b_ih[u] + b_hh[u];
            #pragma unroll
            for (int f4 = 0; f4 < 32; ++f4) {
                float4 wv = wr[f4];
                float4 dv = dyn4[f4];
                za += wv.x * dv.x + wv.y * dv.y + wv.z * dv.z + wv.w * dv.w;
            }
            z4[(((size_t)(b * 8 + ch) * 128 + h) * 4 + qg) * 16 + si] = za;
        }
    }
}

// ---------------------------------------------------------------------------
// K2 fused: blocks [0,4) = LSTM recurrence; [4,2052) = gather.
// ---------------------------------------------------------------------------
__global__ __launch_bounds__(512) void k_lstm_gather(
        const float* __restrict__ z4, const float* __restrict__ w_hh,
        float* __restrict__ lw,
        const float* __restrict__ x, const float* __restrict__ d_inv,
        const int* __restrict__ cnt, const int* __restrict__ idx,
        float* __restrict__ agg) {
    if (blockIdx.x < 4) {
        const int b = blockIdx.x;
        const int t = threadIdx.x;
        const int m = t >> 2;
        const int q = t & 3;
        __shared__ __align__(16) h2 hbuf[2][64];   // 128 f16 h per buffer
        h2 w2[4][16];
        #pragma unroll
        for (int g = 0; g < 4; ++g) {
            const float4* wr = (const float4*)(w_hh + ((size_t)(g * HIDN + m)) * HIDN + q * 32);
            #pragma unroll
            for (int j4 = 0; j4 < 8; ++j4) {
                float4 wv = wr[j4];
                w2[g][2 * j4 + 0] = h2{(_Float16)wv.x, (_Float16)wv.y};
                w2[g][2 * j4 + 1] = h2{(_Float16)wv.z, (_Float16)wv.w};
            }
        }
        float c = 0.0f;
        if (t < 64) hbuf[0][t] = h2{(_Float16)0.0f, (_Float16)0.0f};
        __syncthreads();
        for (int ch = 0; ch < 8; ++ch) {
            const float4* zc = (const float4*)(z4 + ((((size_t)(b * 8 + ch) * 128 + m) * 4 + q) * 16));
            float4 zr0 = zc[0], zr1 = zc[1], zr2 = zc[2], zr3 = zc[3];
            float zs[16] = {zr0.x, zr0.y, zr0.z, zr0.w, zr1.x, zr1.y, zr1.z, zr1.w,
                            zr2.x, zr2.y, zr2.z, zr2.w, zr3.x, zr3.y, zr3.z, zr3.w};
            float hist[16];
            #pragma unroll
            for (int si = 0; si < 16; ++si) {
                const int s = ch * 16 + si;
                const h8* hq8 = ((const h8*)hbuf[s & 1]) + q * 4;
                h8 H0 = hq8[0], H1 = hq8[1], H2 = hq8[2], H3 = hq8[3];
                h2 hh[16];
                #pragma unroll
                for (int j = 0; j < 4; ++j) {
                    hh[j]      = ((const h2*)&H0)[j];
                    hh[4 + j]  = ((const h2*)&H1)[j];
                    hh[8 + j]  = ((const h2*)&H2)[j];
                    hh[12 + j] = ((const h2*)&H3)[j];
                }
                float zq = zs[si];
                float a0 = (q == 0) ? zq : 0.0f, b0 = 0.0f;
                float a1 = (q == 1) ? zq : 0.0f, b1 = 0.0f;
                float a2 = (q == 2) ? zq : 0.0f, b2 = 0.0f;
                float a3 = (q == 3) ? zq : 0.0f, b3 = 0.0f;
                #pragma unroll
                for (int j = 0; j < 8; ++j) {
                    a0 = __builtin_amdgcn_fdot2(w2[0][2 * j], hh[2 * j], a0, false);
                    b0 = __builtin_amdgcn_fdot2(w2[0][2 * j + 1], hh[2 * j + 1], b0, false);
                    a1 = __builtin_amdgcn_fdot2(w2[1][2 * j], hh[2 * j], a1, false);
                    b1 = __builtin_amdgcn_fdot2(w2[1][2 * j + 1], hh[2 * j + 1], b1, false);
                    a2 = __builtin_amdgcn_fdot2(w2[2][2 * j], hh[2 * j], a2, false);
                    b2 = __builtin_amdgcn_fdot2(w2[2][2 * j + 1], hh[2 * j + 1], b2, false);
                    a3 = __builtin_amdgcn_fdot2(w2[3][2 * j], hh[2 * j], a3, false);
                    b3 = __builtin_amdgcn_fdot2(w2[3][2 * j + 1], hh[2 * j + 1], b3, false);
                }
                float z0 = a0 + b0, z1 = a1 + b1, z2 = a2 + b2, z3 = a3 + b3;
                z0 += __shfl_xor(z0, 1); z0 += __shfl_xor(z0, 2);
                z1 += __shfl_xor(z1, 1); z1 += __shfl_xor(z1, 2);
                z2 += __shfl_xor(z2, 1); z2 += __shfl_xor(z2, 2);
                z3 += __shfl_xor(z3, 1); z3 += __shfl_xor(z3, 2);
                float ig = fsig(z0);
                float fg = fsig(z1);
                float gg = ftanh_(z2);
                float og = fsig(z3);
                c = fg * c + ig * gg;
                float hn = og * ftanh_(c);
                hist[si] = hn;
                if (q == 0) ((_Float16*)hbuf[(s + 1) & 1])[m] = (_Float16)hn;
                __syncthreads();
            }
            float* lwb = lw + ((size_t)b * HIDN + ch * 16) * HIDN + m;
            #pragma unroll
            for (int qq = 0; qq < 4; ++qq) {
                if (q == qq) {
                    #pragma unroll
                    for (int k = 0; k < 4; ++k)
                        lwb[(size_t)(qq * 4 + k) * HIDN] = hist[qq * 4 + k];
                }
            }
        }
    } else {
        // ---- gather: 8 waves = 8 rows per block, XCD batch pinning ----
        const int gIdx = blockIdx.x - 4;
        const int b = (gIdx & 7) >> 1;             // batch pinned to XCD pair
        const int o = ((gIdx >> 3) << 1) | (gIdx & 1); // ordinal [0,512)
        const int wid = threadIdx.x >> 6;
        const int lane = threadIdx.x & 63;
        __shared__ __align__(16) float dl[N_NODES];
        {
            const float4* dsrc = (const float4*)(d_inv + (b << 12));
            float4* ddst = (float4*)dl;
            ddst[threadIdx.x] = dsrc[threadIdx.x];
            ddst[threadIdx.x + 512] = dsrc[threadIdx.x + 512];
        }
        __syncthreads();
        const int i = o * 8 + wid;                 // row within batch
        const int r = (b << 12) + i;
        const float2* xb = (const float2*)(x + (size_t)b * N_NODES * HIDN);
        const int* irow = idx + r * MAXNZ;
        const int n = cnt[r];
        float ax = 0.0f, ay = 0.0f;
        int k = 0;
        for (; k + 8 <= n; k += 8) {
            int4 j0 = *(const int4*)&irow[k];
            int4 j1 = *(const int4*)&irow[k + 4];
            float2 v0 = xb[(size_t)j0.x * 64 + lane];
            float2 v1 = xb[(size_t)j0.y * 64 + lane];
            float2 v2 = xb[(size_t)j0.z * 64 + lane];
            float2 v3 = xb[(size_t)j0.w * 64 + lane];
            float2 v4 = xb[(size_t)j1.x * 64 + lane];
            float2 v5 = xb[(size_t)j1.y * 64 + lane];
            float2 v6 = xb[(size_t)j1.z * 64 + lane];
            float2 v7 = xb[(size_t)j1.w * 64 + lane];
            float d0 = dl[j0.x], d1 = dl[j0.y], d2 = dl[j0.z], d3 = dl[j0.w];
            float d4 = dl[j1.x], d5 = dl[j1.y], d6 = dl[j1.z], d7 = dl[j1.w];
            ax += d0 * v0.x + d1 * v1.x + d2 * v2.x + d3 * v3.x
                + d4 * v4.x + d5 * v5.x + d6 * v6.x + d7 * v7.x;
            ay += d0 * v0.y + d1 * v1.y + d2 * v2.y + d3 * v3.y
                + d4 * v4.y + d5 * v5.y + d6 * v6.y + d7 * v7.y;
        }
        for (; k < n; ++k) {
            int j = irow[k];
            float dj = dl[j];
            float2 v = xb[(size_t)j * 64 + lane];
            ax += dj * v.x;
            ay += dj * v.y;
        }
        float di = dl[i];
        float2 vi = xb[(size_t)i * 64 + lane];
        float2 o2;
        o2.x = di * (ax + di * vi.x);
        o2.y = di * (ay + di * vi.y);
        ((float2*)(agg + (size_t)r * HIDN))[lane] = o2;
    }
}

// ---------------------------------------------------------------------------
// K3: out = sigmoid(agg @ lw[b]). lw (64 KB) staged in LDS, 64 rows/block.
// ---------------------------------------------------------------------------
__global__ __launch_bounds__(256) void k_outmm(
        const float* __restrict__ agg, const float* __restrict__ lw,
        float* __restrict__ out) {
    __shared__ __align__(16) float lw_lds[HIDN * HIDN];
    const int i0 = blockIdx.x * 64;
    const int b = i0 >> 12;
    const float4* lwg = (const float4*)(lw + (size_t)b * HIDN * HIDN);
    float4* lds4 = (float4*)lw_lds;
    for (int v = threadIdx.x; v < HIDN * HIDN / 4; v += 256) lds4[v] = lwg[v];
    __syncthreads();
    const int r0 = i0 + (threadIdx.x >> 3) * 2;
    const int u0 = (threadIdx.x & 7) * 16;
    const float4* a4 = (const float4*)agg;
    float4 acc[2][4];
    #pragma unroll
    for (int rr = 0; rr < 2; ++rr)
        #pragma unroll
        for (int cc = 0; cc < 4; ++cc) acc[rr][cc] = make_float4(0.f, 0.f, 0.f, 0.f);
    for (int f4 = 0; f4 < 32; ++f4) {
        float4 a0 = a4[(size_t)r0 * 32 + f4];
        float4 a1 = a4[(size_t)(r0 + 1) * 32 + f4];
        #pragma unroll
        for (int ff = 0; ff < 4; ++ff) {
            float af0 = (ff == 0) ? a0.x : (ff == 1) ? a0.y : (ff == 2) ? a0.z : a0.w;
            float af1 = (ff == 0) ? a1.x : (ff == 1) ? a1.y : (ff == 2) ? a1.z : a1.w;
            int f = f4 * 4 + ff;
            const float4* wrow = (const float4*)(lw_lds + f * HIDN + u0);
            #pragma unroll
            for (int cc = 0; cc < 4; ++cc) {
                float4 wv = wrow[cc];
                acc[0][cc].x += af0 * wv.x; acc[0][cc].y += af0 * wv.y;
                acc[0][cc].z += af0 * wv.z; acc[0][cc].w += af0 * wv.w;
                acc[1][cc].x += af1 * wv.x; acc[1][cc].y += af1 * wv.y;
                acc[1][cc].z += af1 * wv.z; acc[1][cc].w += af1 * wv.w;
            }
        }
    }
    #pragma unroll
    for (int rr = 0; rr < 2; ++rr) {
        #pragma unroll
        for (int cc = 0; cc < 4; ++cc) {
            float4 ov;
            ov.x = fsig(acc[rr][cc].x);
            ov.y = fsig(acc[rr][cc].y);
            ov.z = fsig(acc[rr][cc].z);
            ov.w = fsig(acc[rr][cc].w);
            *(float4*)(out + (size_t)(r0 + rr) * HIDN + u0 + cc * 4) = ov;
        }
    }
}

// ---------------------------------------------------------------------------
extern "C" void kernel_launch(void* const* d_in, const int* in_sizes, int n_in,
                              void* d_out, int out_size, void* d_ws, size_t ws_size,
                              hipStream_t stream) {
    const float* x      = (const float*)d_in[0];
    const float* A      = (const float*)d_in[1];
    const float* conv_w = (const float*)d_in[2];
    const float* conv_b = (const float*)d_in[3];
    const float* w_ih   = (const float*)d_in[4];
    const float* w_hh   = (const float*)d_in[5];
    const float* b_ih   = (const float*)d_in[6];
    const float* b_hh   = (const float*)d_in[7];
    float* out = (float*)d_out;

    char* ws = (char*)d_ws;
    float* d_inv = (float*)ws;                                   // 64 KB
    int*   cnt   = (int*)(ws + 65536);                           // 64 KB
    int*   idx   = (int*)(ws + 131072);                          // 8 MB
    float* z4    = (float*)(ws + 131072 + 8388608);              // 1 MB
    float* lw    = (float*)(ws + 131072 + 8388608 + 1048576);    // 256 KB
    float* agg   = (float*)(ws + 131072 + 8388608 + 1048576 + 262144); // 8 MB

    hipLaunchKernelGGL(k_scan_conv, dim3(2176), dim3(512), 0, stream,
                       A, d_inv, cnt, idx,
                       x, conv_w, conv_b, w_ih, b_ih, b_hh, z4);
    hipLaunchKernelGGL(k_lstm_gather, dim3(2052), dim3(512), 0, stream,
                       z4, w_hh, lw, x, d_inv, cnt, idx, agg);
    hipLaunchKernelGGL(k_outmm, dim3(256), dim3(256), 0, stream, agg, lw, out);
}

// Round 8
// 528.834 us; speedup vs baseline: 1.0637x; 1.0637x over previous
//
#include <hip/hip_runtime.h>
#include <math.h>

#define N_NODES 4096
#define HIDN 128
#define MAXNZ 128

typedef float v4f __attribute__((ext_vector_type(4)));
typedef _Float16 h2 __attribute__((ext_vector_type(2)));
typedef _Float16 h8 __attribute__((ext_vector_type(8)));

__device__ __forceinline__ float fsig(float x) { return 1.0f / (1.0f + __expf(-x)); }
__device__ __forceinline__ float ftanh_(float x) { return 1.0f - 2.0f / (__expf(2.0f * x) + 1.0f); }

// ---------------------------------------------------------------------------
// K1: conv1d + z precompute. 128 blocks x 512 thr (4 timesteps/block).
// dyn phase: thread=(tsub,h). z phase: thread = u (each w_ih row read ONCE
// per block, in two 16-float4 register chunks; 4 independent t-chains;
// one aligned float4 store per thread).
// z layout: z4[b][chunk:8][cell:128][gate:4][s:16].
// ---------------------------------------------------------------------------
__global__ __launch_bounds__(512) void k_convz(
        const float* __restrict__ x, const float* __restrict__ conv_w,
        const float* __restrict__ conv_b, const float* __restrict__ w_ih,
        const float* __restrict__ b_ih, const float* __restrict__ b_hh,
        float* __restrict__ z4) {
    const int cb = blockIdx.x;
    const int b = cb >> 5;
    const int t0 = (cb & 31) * 4;
    const int tsub = threadIdx.x >> 7;
    const int h = threadIdx.x & 127;
    const int t = t0 + tsub;                       // timestep 0..127
    __shared__ __align__(16) float dyn_lds[4][HIDN];
    {
        const float* xb = x + ((size_t)b * N_NODES + (N_NODES - HIDN)) * HIDN;
        const float* w = conv_w + (size_t)t * HIDN * 3;
        float a0 = conv_b[t], a1 = 0.0f, a2 = 0.0f, a3 = 0.0f;
        #pragma unroll 4
        for (int i = 0; i < HIDN; i += 4) {
            const float* xr0 = xb + (size_t)i * HIDN;
            #pragma unroll
            for (int s = 0; s < 4; ++s) {
                const float* xr = xr0 + s * HIDN;
                float w0 = w[(i + s) * 3 + 0], w1 = w[(i + s) * 3 + 1], w2 = w[(i + s) * 3 + 2];
                float left  = (h > 0)   ? xr[h - 1] : 0.0f;
                float mid   = xr[h];
                float right = (h < 127) ? xr[h + 1] : 0.0f;
                if (s == 0)      a0 += left * w0 + mid * w1 + right * w2;
                else if (s == 1) a1 += left * w0 + mid * w1 + right * w2;
                else if (s == 2) a2 += left * w0 + mid * w1 + right * w2;
                else             a3 += left * w0 + mid * w1 + right * w2;
            }
        }
        dyn_lds[tsub][h] = (a0 + a1) + (a2 + a3);
    }
    __syncthreads();
    // ---- z phase: thread = u = gate*128 + cell ----
    const int u = threadIdx.x;
    const int qg = u >> 7;                         // gate
    const int m  = u & 127;                        // cell
    const float4* wr = (const float4*)(w_ih + (size_t)u * HIDN);
    float bias = b_ih[u] + b_hh[u];
    float acc0 = bias, acc1 = bias, acc2 = bias, acc3 = bias;
    #pragma unroll
    for (int half = 0; half < 2; ++half) {
        float4 wv[16];
        #pragma unroll
        for (int j = 0; j < 16; ++j) wv[j] = wr[half * 16 + j];
        const float4* d0 = (const float4*)dyn_lds[0] + half * 16;
        const float4* d1 = (const float4*)dyn_lds[1] + half * 16;
        const float4* d2 = (const float4*)dyn_lds[2] + half * 16;
        const float4* d3 = (const float4*)dyn_lds[3] + half * 16;
        #pragma unroll
        for (int j = 0; j < 16; ++j) {
            float4 wj = wv[j];
            float4 v0 = d0[j], v1 = d1[j], v2 = d2[j], v3 = d3[j];
            acc0 += wj.x * v0.x + wj.y * v0.y + wj.z * v0.z + wj.w * v0.w;
            acc1 += wj.x * v1.x + wj.y * v1.y + wj.z * v1.z + wj.w * v1.w;
            acc2 += wj.x * v2.x + wj.y * v2.y + wj.z * v2.z + wj.w * v2.w;
            acc3 += wj.x * v3.x + wj.y * v3.y + wj.z * v3.z + wj.w * v3.w;
        }
    }
    const int ch = t0 >> 4, si0 = t0 & 15;         // all 4 t's in same chunk
    float4 st = make_float4(acc0, acc1, acc2, acc3);
    *(float4*)&z4[((((size_t)(b * 8 + ch)) * 128 + m) * 4 + qg) * 16 + si0] = st;
}

// ---------------------------------------------------------------------------
// K2: A-scan standalone. 4096 blocks x 256 thr (4 rows/block), software-
// pipelined groups of 4 float4 loads (low VGPR -> 8 waves/SIMD for MLP),
// LDS-buffered coalesced idx flush.
// ---------------------------------------------------------------------------
__global__ __launch_bounds__(256) void k_scan(
        const float* __restrict__ A, float* __restrict__ d_inv,
        int* __restrict__ cnt, int* __restrict__ idx) {
    const int wid = threadIdx.x >> 6;
    const int lane = threadIdx.x & 63;
    const int r = blockIdx.x * 4 + wid;
    const v4f* row = (const v4f*)(A + (size_t)r * N_NODES);
    __shared__ int sidx[4][MAXNZ];
    const unsigned long long below = (1ull << lane) - 1ull;
    int cbase = 0;
    v4f cur[4], nxt[4];
    #pragma unroll
    for (int j = 0; j < 4; ++j) cur[j] = row[j * 64 + lane];
#define PROC1(c, col)                                                         \
    {                                                                         \
        bool nz = ((c) != 0.0f);                                              \
        unsigned long long mm = __ballot(nz);                                 \
        if (mm) {                                                             \
            if (nz) {                                                         \
                int p_ = cbase + __popcll(mm & below);                        \
                if (p_ < MAXNZ) sidx[wid][p_] = (col);                        \
            }                                                                 \
            cbase += __popcll(mm);                                            \
        }                                                                     \
    }
    #pragma unroll
    for (int g = 0; g < 4; ++g) {
        if (g < 3) {
            #pragma unroll
            for (int j = 0; j < 4; ++j) nxt[j] = row[(g + 1) * 256 + j * 64 + lane];
        }
        #pragma unroll
        for (int j = 0; j < 4; ++j) {
            int col0 = ((g * 4 + j) * 64 + lane) * 4;
            PROC1(cur[j].x, col0 + 0);
            PROC1(cur[j].y, col0 + 1);
            PROC1(cur[j].z, col0 + 2);
            PROC1(cur[j].w, col0 + 3);
        }
        #pragma unroll
        for (int j = 0; j < 4; ++j) cur[j] = nxt[j];
    }
#undef PROC1
    int cnt_r = (cbase < MAXNZ) ? cbase : MAXNZ;
    for (int k = lane; k < cnt_r; k += 64)
        idx[r * MAXNZ + k] = sidx[wid][k];
    if (lane == 0) {
        cnt[r] = cnt_r;
        d_inv[r] = rsqrtf((float)(cbase + 1));
    }
}

// ---------------------------------------------------------------------------
// K3 fused: blocks [0,4) = LSTM recurrence; [4,2052) = gather.
// ---------------------------------------------------------------------------
__global__ __launch_bounds__(512) void k_lstm_gather(
        const float* __restrict__ z4, const float* __restrict__ w_hh,
        float* __restrict__ lw,
        const float* __restrict__ x, const float* __restrict__ d_inv,
        const int* __restrict__ cnt, const int* __restrict__ idx,
        float* __restrict__ agg) {
    if (blockIdx.x < 4) {
        const int b = blockIdx.x;
        const int t = threadIdx.x;
        const int m = t >> 2;
        const int q = t & 3;
        __shared__ __align__(16) h2 hbuf[2][64];   // 128 f16 h per buffer
        h2 w2[4][16];
        #pragma unroll
        for (int g = 0; g < 4; ++g) {
            const float4* wr = (const float4*)(w_hh + ((size_t)(g * HIDN + m)) * HIDN + q * 32);
            #pragma unroll
            for (int j4 = 0; j4 < 8; ++j4) {
                float4 wv = wr[j4];
                w2[g][2 * j4 + 0] = h2{(_Float16)wv.x, (_Float16)wv.y};
                w2[g][2 * j4 + 1] = h2{(_Float16)wv.z, (_Float16)wv.w};
            }
        }
        float c = 0.0f;
        if (t < 64) hbuf[0][t] = h2{(_Float16)0.0f, (_Float16)0.0f};
        __syncthreads();
        for (int ch = 0; ch < 8; ++ch) {
            const float4* zc = (const float4*)(z4 + ((((size_t)(b * 8 + ch) * 128 + m) * 4 + q) * 16));
            float4 zr0 = zc[0], zr1 = zc[1], zr2 = zc[2], zr3 = zc[3];
            float zs[16] = {zr0.x, zr0.y, zr0.z, zr0.w, zr1.x, zr1.y, zr1.z, zr1.w,
                            zr2.x, zr2.y, zr2.z, zr2.w, zr3.x, zr3.y, zr3.z, zr3.w};
            float hist[16];
            #pragma unroll
            for (int si = 0; si < 16; ++si) {
                const int s = ch * 16 + si;
                const h8* hq8 = ((const h8*)hbuf[s & 1]) + q * 4;
                h8 H0 = hq8[0], H1 = hq8[1], H2 = hq8[2], H3 = hq8[3];
                h2 hh[16];
                #pragma unroll
                for (int j = 0; j < 4; ++j) {
                    hh[j]      = ((const h2*)&H0)[j];
                    hh[4 + j]  = ((const h2*)&H1)[j];
                    hh[8 + j]  = ((const h2*)&H2)[j];
                    hh[12 + j] = ((const h2*)&H3)[j];
                }
                float zq = zs[si];
                float a0 = (q == 0) ? zq : 0.0f, b0 = 0.0f;
                float a1 = (q == 1) ? zq : 0.0f, b1 = 0.0f;
                float a2 = (q == 2) ? zq : 0.0f, b2 = 0.0f;
                float a3 = (q == 3) ? zq : 0.0f, b3 = 0.0f;
                #pragma unroll
                for (int j = 0; j < 8; ++j) {
                    a0 = __builtin_amdgcn_fdot2(w2[0][2 * j], hh[2 * j], a0, false);
                    b0 = __builtin_amdgcn_fdot2(w2[0][2 * j + 1], hh[2 * j + 1], b0, false);
                    a1 = __builtin_amdgcn_fdot2(w2[1][2 * j], hh[2 * j], a1, false);
                    b1 = __builtin_amdgcn_fdot2(w2[1][2 * j + 1], hh[2 * j + 1], b1, false);
                    a2 = __builtin_amdgcn_fdot2(w2[2][2 * j], hh[2 * j], a2, false);
                    b2 = __builtin_amdgcn_fdot2(w2[2][2 * j + 1], hh[2 * j + 1], b2, false);
                    a3 = __builtin_amdgcn_fdot2(w2[3][2 * j], hh[2 * j], a3, false);
                    b3 = __builtin_amdgcn_fdot2(w2[3][2 * j + 1], hh[2 * j + 1], b3, false);
                }
                float z0 = a0 + b0, z1 = a1 + b1, z2 = a2 + b2, z3 = a3 + b3;
                z0 += __shfl_xor(z0, 1); z0 += __shfl_xor(z0, 2);
                z1 += __shfl_xor(z1, 1); z1 += __shfl_xor(z1, 2);
                z2 += __shfl_xor(z2, 1); z2 += __shfl_xor(z2, 2);
                z3 += __shfl_xor(z3, 1); z3 += __shfl_xor(z3, 2);
                float ig = fsig(z0);
                float fg = fsig(z1);
                float gg = ftanh_(z2);
                float og = fsig(z3);
                c = fg * c + ig * gg;
                float hn = og * ftanh_(c);
                hist[si] = hn;
                if (q == 0) ((_Float16*)hbuf[(s + 1) & 1])[m] = (_Float16)hn;
                __syncthreads();
            }
            float* lwb = lw + ((size_t)b * HIDN + ch * 16) * HIDN + m;
            #pragma unroll
            for (int qq = 0; qq < 4; ++qq) {
                if (q == qq) {
                    #pragma unroll
                    for (int k = 0; k < 4; ++k)
                        lwb[(size_t)(qq * 4 + k) * HIDN] = hist[qq * 4 + k];
                }
            }
        }
    } else {
        // ---- gather: 8 waves = 8 rows per block, XCD batch pinning ----
        const int gIdx = blockIdx.x - 4;
        const int b = (gIdx & 7) >> 1;             // batch pinned to XCD pair
        const int o = ((gIdx >> 3) << 1) | (gIdx & 1); // ordinal [0,512)
        const int wid = threadIdx.x >> 6;
        const int lane = threadIdx.x & 63;
        __shared__ __align__(16) float dl[N_NODES];
        {
            const float4* dsrc = (const float4*)(d_inv + (b << 12));
            float4* ddst = (float4*)dl;
            ddst[threadIdx.x] = dsrc[threadIdx.x];
            ddst[threadIdx.x + 512] = dsrc[threadIdx.x + 512];
        }
        __syncthreads();
        const int i = o * 8 + wid;                 // row within batch
        const int r = (b << 12) + i;
        const float2* xb = (const float2*)(x + (size_t)b * N_NODES * HIDN);
        const int* irow = idx + r * MAXNZ;
        const int n = cnt[r];
        float ax = 0.0f, ay = 0.0f;
        int k = 0;
        for (; k + 8 <= n; k += 8) {
            int4 j0 = *(const int4*)&irow[k];
            int4 j1 = *(const int4*)&irow[k + 4];
            float2 v0 = xb[(size_t)j0.x * 64 + lane];
            float2 v1 = xb[(size_t)j0.y * 64 + lane];
            float2 v2 = xb[(size_t)j0.z * 64 + lane];
            float2 v3 = xb[(size_t)j0.w * 64 + lane];
            float2 v4 = xb[(size_t)j1.x * 64 + lane];
            float2 v5 = xb[(size_t)j1.y * 64 + lane];
            float2 v6 = xb[(size_t)j1.z * 64 + lane];
            float2 v7 = xb[(size_t)j1.w * 64 + lane];
            float d0 = dl[j0.x], d1 = dl[j0.y], d2 = dl[j0.z], d3 = dl[j0.w];
            float d4 = dl[j1.x], d5 = dl[j1.y], d6 = dl[j1.z], d7 = dl[j1.w];
            ax += d0 * v0.x + d1 * v1.x + d2 * v2.x + d3 * v3.x
                + d4 * v4.x + d5 * v5.x + d6 * v6.x + d7 * v7.x;
            ay += d0 * v0.y + d1 * v1.y + d2 * v2.y + d3 * v3.y
                + d4 * v4.y + d5 * v5.y + d6 * v6.y + d7 * v7.y;
        }
        for (; k < n; ++k) {
            int j = irow[k];
            float dj = dl[j];
            float2 v = xb[(size_t)j * 64 + lane];
            ax += dj * v.x;
            ay += dj * v.y;
        }
        float di = dl[i];
        float2 vi = xb[(size_t)i * 64 + lane];
        float2 o2;
        o2.x = di * (ax + di * vi.x);
        o2.y = di * (ay + di * vi.y);
        ((float2*)(agg + (size_t)r * HIDN))[lane] = o2;
    }
}

// ---------------------------------------------------------------------------
// K4: out = sigmoid(agg @ lw[b]). lw (64 KB) staged in LDS, 64 rows/block.
// ---------------------------------------------------------------------------
__global__ __launch_bounds__(256) void k_outmm(
        const float* __restrict__ agg, const float* __restrict__ lw,
        float* __restrict__ out) {
    __shared__ __align__(16) float lw_lds[HIDN * HIDN];
    const int i0 = blockIdx.x * 64;
    const int b = i0 >> 12;
    const float4* lwg = (const float4*)(lw + (size_t)b * HIDN * HIDN);
    float4* lds4 = (float4*)lw_lds;
    for (int v = threadIdx.x; v < HIDN * HIDN / 4; v += 256) lds4[v] = lwg[v];
    __syncthreads();
    const int r0 = i0 + (threadIdx.x >> 3) * 2;
    const int u0 = (threadIdx.x & 7) * 16;
    const float4* a4 = (const float4*)agg;
    float4 acc[2][4];
    #pragma unroll
    for (int rr = 0; rr < 2; ++rr)
        #pragma unroll
        for (int cc = 0; cc < 4; ++cc) acc[rr][cc] = make_float4(0.f, 0.f, 0.f, 0.f);
    for (int f4 = 0; f4 < 32; ++f4) {
        float4 a0 = a4[(size_t)r0 * 32 + f4];
        float4 a1 = a4[(size_t)(r0 + 1) * 32 + f4];
        #pragma unroll
        for (int ff = 0; ff < 4; ++ff) {
            float af0 = (ff == 0) ? a0.x : (ff == 1) ? a0.y : (ff == 2) ? a0.z : a0.w;
            float af1 = (ff == 0) ? a1.x : (ff == 1) ? a1.y : (ff == 2) ? a1.z : a1.w;
            int f = f4 * 4 + ff;
            const float4* wrow = (const float4*)(lw_lds + f * HIDN + u0);
            #pragma unroll
            for (int cc = 0; cc < 4; ++cc) {
                float4 wv = wrow[cc];
                acc[0][cc].x += af0 * wv.x; acc[0][cc].y += af0 * wv.y;
                acc[0][cc].z += af0 * wv.z; acc[0][cc].w += af0 * wv.w;
                acc[1][cc].x += af1 * wv.x; acc[1][cc].y += af1 * wv.y;
                acc[1][cc].z += af1 * wv.z; acc[1][cc].w += af1 * wv.w;
            }
        }
    }
    #pragma unroll
    for (int rr = 0; rr < 2; ++rr) {
        #pragma unroll
        for (int cc = 0; cc < 4; ++cc) {
            float4 ov;
            ov.x = fsig(acc[rr][cc].x);
            ov.y = fsig(acc[rr][cc].y);
            ov.z = fsig(acc[rr][cc].z);
            ov.w = fsig(acc[rr][cc].w);
            *(float4*)(out + (size_t)(r0 + rr) * HIDN + u0 + cc * 4) = ov;
        }
    }
}

// ---------------------------------------------------------------------------
extern "C" void kernel_launch(void* const* d_in, const int* in_sizes, int n_in,
                              void* d_out, int out_size, void* d_ws, size_t ws_size,
                              hipStream_t stream) {
    const float* x      = (const float*)d_in[0];
    const float* A      = (const float*)d_in[1];
    const float* conv_w = (const float*)d_in[2];
    const float* conv_b = (const float*)d_in[3];
    const float* w_ih   = (const float*)d_in[4];
    const float* w_hh   = (const float*)d_in[5];
    const float* b_ih   = (const float*)d_in[6];
    const float* b_hh   = (const float*)d_in[7];
    float* out = (float*)d_out;

    char* ws = (char*)d_ws;
    float* d_inv = (float*)ws;                                   // 64 KB
    int*   cnt   = (int*)(ws + 65536);                           // 64 KB
    int*   idx   = (int*)(ws + 131072);                          // 8 MB
    float* z4    = (float*)(ws + 131072 + 8388608);              // 1 MB
    float* lw    = (float*)(ws + 131072 + 8388608 + 1048576);    // 256 KB
    float* agg   = (float*)(ws + 131072 + 8388608 + 1048576 + 262144); // 8 MB

    hipLaunchKernelGGL(k_convz, dim3(128), dim3(512), 0, stream,
                       x, conv_w, conv_b, w_ih, b_ih, b_hh, z4);
    hipLaunchKernelGGL(k_scan, dim3(4096), dim3(256), 0, stream,
                       A, d_inv, cnt, idx);
    hipLaunchKernelGGL(k_lstm_gather, dim3(2052), dim3(512), 0, stream,
                       z4, w_hh, lw, x, d_inv, cnt, idx, agg);
    hipLaunchKernelGGL(k_outmm, dim3(256), dim3(256), 0, stream, agg, lw, out);
}

// Round 9
// 505.947 us; speedup vs baseline: 1.1118x; 1.0452x over previous
//
#include <hip/hip_runtime.h>
#include <math.h>

#define N_NODES 4096
#define HIDN 128
#define MAXNZ 128

typedef float v4f __attribute__((ext_vector_type(4)));
typedef _Float16 h2 __attribute__((ext_vector_type(2)));
typedef _Float16 h8 __attribute__((ext_vector_type(8)));

__device__ __forceinline__ float fsig(float x) { return 1.0f / (1.0f + __expf(-x)); }
__device__ __forceinline__ float ftanh_(float x) { return 1.0f - 2.0f / (__expf(2.0f * x) + 1.0f); }

// ---------------------------------------------------------------------------
// K1: conv1d + z precompute. 128 blocks x 512 thr (4 timesteps/block).
// z phase: thread = u; each w_ih row read once per block.
// z layout: z4[b][chunk:8][cell:128][gate:4][s:16].
// ---------------------------------------------------------------------------
__global__ __launch_bounds__(512) void k_convz(
        const float* __restrict__ x, const float* __restrict__ conv_w,
        const float* __restrict__ conv_b, const float* __restrict__ w_ih,
        const float* __restrict__ b_ih, const float* __restrict__ b_hh,
        float* __restrict__ z4) {
    const int cb = blockIdx.x;
    const int b = cb >> 5;
    const int t0 = (cb & 31) * 4;
    const int tsub = threadIdx.x >> 7;
    const int h = threadIdx.x & 127;
    const int t = t0 + tsub;                       // timestep 0..127
    __shared__ __align__(16) float dyn_lds[4][HIDN];
    {
        const float* xb = x + ((size_t)b * N_NODES + (N_NODES - HIDN)) * HIDN;
        const float* w = conv_w + (size_t)t * HIDN * 3;
        float a0 = conv_b[t], a1 = 0.0f, a2 = 0.0f, a3 = 0.0f;
        #pragma unroll 4
        for (int i = 0; i < HIDN; i += 4) {
            const float* xr0 = xb + (size_t)i * HIDN;
            #pragma unroll
            for (int s = 0; s < 4; ++s) {
                const float* xr = xr0 + s * HIDN;
                float w0 = w[(i + s) * 3 + 0], w1 = w[(i + s) * 3 + 1], w2 = w[(i + s) * 3 + 2];
                float left  = (h > 0)   ? xr[h - 1] : 0.0f;
                float mid   = xr[h];
                float right = (h < 127) ? xr[h + 1] : 0.0f;
                if (s == 0)      a0 += left * w0 + mid * w1 + right * w2;
                else if (s == 1) a1 += left * w0 + mid * w1 + right * w2;
                else if (s == 2) a2 += left * w0 + mid * w1 + right * w2;
                else             a3 += left * w0 + mid * w1 + right * w2;
            }
        }
        dyn_lds[tsub][h] = (a0 + a1) + (a2 + a3);
    }
    __syncthreads();
    // ---- z phase: thread = u = gate*128 + cell ----
    const int u = threadIdx.x;
    const int qg = u >> 7;                         // gate
    const int m  = u & 127;                        // cell
    const float4* wr = (const float4*)(w_ih + (size_t)u * HIDN);
    float bias = b_ih[u] + b_hh[u];
    float acc0 = bias, acc1 = bias, acc2 = bias, acc3 = bias;
    #pragma unroll
    for (int half = 0; half < 2; ++half) {
        float4 wv[16];
        #pragma unroll
        for (int j = 0; j < 16; ++j) wv[j] = wr[half * 16 + j];
        const float4* d0 = (const float4*)dyn_lds[0] + half * 16;
        const float4* d1 = (const float4*)dyn_lds[1] + half * 16;
        const float4* d2 = (const float4*)dyn_lds[2] + half * 16;
        const float4* d3 = (const float4*)dyn_lds[3] + half * 16;
        #pragma unroll
        for (int j = 0; j < 16; ++j) {
            float4 wj = wv[j];
            float4 v0 = d0[j], v1 = d1[j], v2 = d2[j], v3 = d3[j];
            acc0 += wj.x * v0.x + wj.y * v0.y + wj.z * v0.z + wj.w * v0.w;
            acc1 += wj.x * v1.x + wj.y * v1.y + wj.z * v1.z + wj.w * v1.w;
            acc2 += wj.x * v2.x + wj.y * v2.y + wj.z * v2.z + wj.w * v2.w;
            acc3 += wj.x * v3.x + wj.y * v3.y + wj.z * v3.z + wj.w * v3.w;
        }
    }
    const int ch = t0 >> 4, si0 = t0 & 15;         // all 4 t's in same chunk
    float4 st = make_float4(acc0, acc1, acc2, acc3);
    *(float4*)&z4[((((size_t)(b * 8 + ch)) * 128 + m) * 4 + qg) * 16 + si0] = st;
}

// ---------------------------------------------------------------------------
// K2 fused: blocks [0,4) = LSTM recurrence; [4,2052) = A-scan (8 rows/block).
// LSTM: thread = (cell m=t>>2, k-quarter q=t&3); z bulk-loaded per 16-step
// chunk; steady-state loop = LDS + regs only; h history flushed per chunk.
// Scan: ballot-compact into LDS, one coalesced idx store per row.
// ---------------------------------------------------------------------------
__global__ __launch_bounds__(512) void k_lstm_scan(
        const float* __restrict__ z4, const float* __restrict__ w_hh,
        float* __restrict__ lw,
        const float* __restrict__ A, float* __restrict__ d_inv,
        int* __restrict__ cnt, int* __restrict__ idx) {
    if (blockIdx.x < 4) {
        const int b = blockIdx.x;
        const int t = threadIdx.x;
        const int m = t >> 2;
        const int q = t & 3;
        __shared__ __align__(16) h2 hbuf[2][64];   // 128 f16 h per buffer
        h2 w2[4][16];
        #pragma unroll
        for (int g = 0; g < 4; ++g) {
            const float4* wr = (const float4*)(w_hh + ((size_t)(g * HIDN + m)) * HIDN + q * 32);
            #pragma unroll
            for (int j4 = 0; j4 < 8; ++j4) {
                float4 wv = wr[j4];
                w2[g][2 * j4 + 0] = h2{(_Float16)wv.x, (_Float16)wv.y};
                w2[g][2 * j4 + 1] = h2{(_Float16)wv.z, (_Float16)wv.w};
            }
        }
        float c = 0.0f;
        if (t < 64) hbuf[0][t] = h2{(_Float16)0.0f, (_Float16)0.0f};
        __syncthreads();
        for (int ch = 0; ch < 8; ++ch) {
            const float4* zc = (const float4*)(z4 + ((((size_t)(b * 8 + ch) * 128 + m) * 4 + q) * 16));
            float4 zr0 = zc[0], zr1 = zc[1], zr2 = zc[2], zr3 = zc[3];
            float zs[16] = {zr0.x, zr0.y, zr0.z, zr0.w, zr1.x, zr1.y, zr1.z, zr1.w,
                            zr2.x, zr2.y, zr2.z, zr2.w, zr3.x, zr3.y, zr3.z, zr3.w};
            float hist[16];
            #pragma unroll
            for (int si = 0; si < 16; ++si) {
                const int s = ch * 16 + si;
                const h8* hq8 = ((const h8*)hbuf[s & 1]) + q * 4;
                h8 H0 = hq8[0], H1 = hq8[1], H2 = hq8[2], H3 = hq8[3];
                h2 hh[16];
                #pragma unroll
                for (int j = 0; j < 4; ++j) {
                    hh[j]      = ((const h2*)&H0)[j];
                    hh[4 + j]  = ((const h2*)&H1)[j];
                    hh[8 + j]  = ((const h2*)&H2)[j];
                    hh[12 + j] = ((const h2*)&H3)[j];
                }
                float zq = zs[si];
                float a0 = (q == 0) ? zq : 0.0f, b0 = 0.0f;
                float a1 = (q == 1) ? zq : 0.0f, b1 = 0.0f;
                float a2 = (q == 2) ? zq : 0.0f, b2 = 0.0f;
                float a3 = (q == 3) ? zq : 0.0f, b3 = 0.0f;
                #pragma unroll
                for (int j = 0; j < 8; ++j) {
                    a0 = __builtin_amdgcn_fdot2(w2[0][2 * j], hh[2 * j], a0, false);
                    b0 = __builtin_amdgcn_fdot2(w2[0][2 * j + 1], hh[2 * j + 1], b0, false);
                    a1 = __builtin_amdgcn_fdot2(w2[1][2 * j], hh[2 * j], a1, false);
                    b1 = __builtin_amdgcn_fdot2(w2[1][2 * j + 1], hh[2 * j + 1], b1, false);
                    a2 = __builtin_amdgcn_fdot2(w2[2][2 * j], hh[2 * j], a2, false);
                    b2 = __builtin_amdgcn_fdot2(w2[2][2 * j + 1], hh[2 * j + 1], b2, false);
                    a3 = __builtin_amdgcn_fdot2(w2[3][2 * j], hh[2 * j], a3, false);
                    b3 = __builtin_amdgcn_fdot2(w2[3][2 * j + 1], hh[2 * j + 1], b3, false);
                }
                float z0 = a0 + b0, z1 = a1 + b1, z2 = a2 + b2, z3 = a3 + b3;
                z0 += __shfl_xor(z0, 1); z0 += __shfl_xor(z0, 2);
                z1 += __shfl_xor(z1, 1); z1 += __shfl_xor(z1, 2);
                z2 += __shfl_xor(z2, 1); z2 += __shfl_xor(z2, 2);
                z3 += __shfl_xor(z3, 1); z3 += __shfl_xor(z3, 2);
                float ig = fsig(z0);
                float fg = fsig(z1);
                float gg = ftanh_(z2);
                float og = fsig(z3);
                c = fg * c + ig * gg;
                float hn = og * ftanh_(c);
                hist[si] = hn;
                if (q == 0) ((_Float16*)hbuf[(s + 1) & 1])[m] = (_Float16)hn;
                __syncthreads();
            }
            float* lwb = lw + ((size_t)b * HIDN + ch * 16) * HIDN + m;
            #pragma unroll
            for (int qq = 0; qq < 4; ++qq) {
                if (q == qq) {
                    #pragma unroll
                    for (int k = 0; k < 4; ++k)
                        lwb[(size_t)(qq * 4 + k) * HIDN] = hist[qq * 4 + k];
                }
            }
        }
    } else {
        // ---- A-scan: 8 waves = 8 rows per block ----
        const int wid = threadIdx.x >> 6;
        const int lane = threadIdx.x & 63;
        const int r = (blockIdx.x - 4) * 8 + wid;
        const v4f* row = (const v4f*)(A + (size_t)r * N_NODES);
        __shared__ int sidx[8][MAXNZ];
        const unsigned long long below = (1ull << lane) - 1ull;
        int cbase = 0;
        v4f cur[4], nxt[4];
        #pragma unroll
        for (int j = 0; j < 4; ++j) cur[j] = row[j * 64 + lane];
#define PROC1(c, col)                                                         \
        {                                                                     \
            bool nz = ((c) != 0.0f);                                          \
            unsigned long long mm = __ballot(nz);                             \
            if (mm) {                                                         \
                if (nz) {                                                     \
                    int p_ = cbase + __popcll(mm & below);                    \
                    if (p_ < MAXNZ) sidx[wid][p_] = (col);                    \
                }                                                             \
                cbase += __popcll(mm);                                        \
            }                                                                 \
        }
        #pragma unroll
        for (int g = 0; g < 4; ++g) {
            if (g < 3) {
                #pragma unroll
                for (int j = 0; j < 4; ++j) nxt[j] = row[(g + 1) * 256 + j * 64 + lane];
            }
            #pragma unroll
            for (int j = 0; j < 4; ++j) {
                int col0 = ((g * 4 + j) * 64 + lane) * 4;
                PROC1(cur[j].x, col0 + 0);
                PROC1(cur[j].y, col0 + 1);
                PROC1(cur[j].z, col0 + 2);
                PROC1(cur[j].w, col0 + 3);
            }
            #pragma unroll
            for (int j = 0; j < 4; ++j) cur[j] = nxt[j];
        }
#undef PROC1
        int cnt_r = (cbase < MAXNZ) ? cbase : MAXNZ;
        for (int k = lane; k < cnt_r; k += 64)
            idx[r * MAXNZ + k] = sidx[wid][k];
        if (lane == 0) {
            cnt[r] = cnt_r;
            d_inv[r] = rsqrtf((float)(cbase + 1));
        }
    }
}

// ---------------------------------------------------------------------------
// K3: gather agg = D^-1/2 (A+I) D^-1/2 x. 2048 blocks x 512 thr (8 rows),
// d_inv in LDS, XCD batch pinning.
// ---------------------------------------------------------------------------
__global__ __launch_bounds__(512) void k_gather(
        const float* __restrict__ x, const float* __restrict__ d_inv,
        const int* __restrict__ cnt, const int* __restrict__ idx,
        float* __restrict__ agg) {
    const int gIdx = blockIdx.x;
    const int b = (gIdx & 7) >> 1;                 // batch pinned to XCD pair
    const int o = ((gIdx >> 3) << 1) | (gIdx & 1); // ordinal [0,512)
    const int wid = threadIdx.x >> 6;
    const int lane = threadIdx.x & 63;
    __shared__ __align__(16) float dl[N_NODES];
    {
        const float4* dsrc = (const float4*)(d_inv + (b << 12));
        float4* ddst = (float4*)dl;
        ddst[threadIdx.x] = dsrc[threadIdx.x];
        ddst[threadIdx.x + 512] = dsrc[threadIdx.x + 512];
    }
    __syncthreads();
    const int i = o * 8 + wid;                     // row within batch
    const int r = (b << 12) + i;
    const float2* xb = (const float2*)(x + (size_t)b * N_NODES * HIDN);
    const int* irow = idx + r * MAXNZ;
    const int n = cnt[r];
    float ax = 0.0f, ay = 0.0f;
    int k = 0;
    for (; k + 8 <= n; k += 8) {
        int4 j0 = *(const int4*)&irow[k];
        int4 j1 = *(const int4*)&irow[k + 4];
        float2 v0 = xb[(size_t)j0.x * 64 + lane];
        float2 v1 = xb[(size_t)j0.y * 64 + lane];
        float2 v2 = xb[(size_t)j0.z * 64 + lane];
        float2 v3 = xb[(size_t)j0.w * 64 + lane];
        float2 v4 = xb[(size_t)j1.x * 64 + lane];
        float2 v5 = xb[(size_t)j1.y * 64 + lane];
        float2 v6 = xb[(size_t)j1.z * 64 + lane];
        float2 v7 = xb[(size_t)j1.w * 64 + lane];
        float d0 = dl[j0.x], d1 = dl[j0.y], d2 = dl[j0.z], d3 = dl[j0.w];
        float d4 = dl[j1.x], d5 = dl[j1.y], d6 = dl[j1.z], d7 = dl[j1.w];
        ax += d0 * v0.x + d1 * v1.x + d2 * v2.x + d3 * v3.x
            + d4 * v4.x + d5 * v5.x + d6 * v6.x + d7 * v7.x;
        ay += d0 * v0.y + d1 * v1.y + d2 * v2.y + d3 * v3.y
            + d4 * v4.y + d5 * v5.y + d6 * v6.y + d7 * v7.y;
    }
    for (; k < n; ++k) {
        int j = irow[k];
        float dj = dl[j];
        float2 v = xb[(size_t)j * 64 + lane];
        ax += dj * v.x;
        ay += dj * v.y;
    }
    float di = dl[i];
    float2 vi = xb[(size_t)i * 64 + lane];
    float2 o2;
    o2.x = di * (ax + di * vi.x);
    o2.y = di * (ay + di * vi.y);
    ((float2*)(agg + (size_t)r * HIDN))[lane] = o2;
}

// ---------------------------------------------------------------------------
// K4: out = sigmoid(agg @ lw[b]). lw (64 KB) staged in LDS, 64 rows/block.
// ---------------------------------------------------------------------------
__global__ __launch_bounds__(256) void k_outmm(
        const float* __restrict__ agg, const float* __restrict__ lw,
        float* __restrict__ out) {
    __shared__ __align__(16) float lw_lds[HIDN * HIDN];
    const int i0 = blockIdx.x * 64;
    const int b = i0 >> 12;
    const float4* lwg = (const float4*)(lw + (size_t)b * HIDN * HIDN);
    float4* lds4 = (float4*)lw_lds;
    for (int v = threadIdx.x; v < HIDN * HIDN / 4; v += 256) lds4[v] = lwg[v];
    __syncthreads();
    const int r0 = i0 + (threadIdx.x >> 3) * 2;
    const int u0 = (threadIdx.x & 7) * 16;
    const float4* a4 = (const float4*)agg;
    float4 acc[2][4];
    #pragma unroll
    for (int rr = 0; rr < 2; ++rr)
        #pragma unroll
        for (int cc = 0; cc < 4; ++cc) acc[rr][cc] = make_float4(0.f, 0.f, 0.f, 0.f);
    for (int f4 = 0; f4 < 32; ++f4) {
        float4 a0 = a4[(size_t)r0 * 32 + f4];
        float4 a1 = a4[(size_t)(r0 + 1) * 32 + f4];
        #pragma unroll
        for (int ff = 0; ff < 4; ++ff) {
            float af0 = (ff == 0) ? a0.x : (ff == 1) ? a0.y : (ff == 2) ? a0.z : a0.w;
            float af1 = (ff == 0) ? a1.x : (ff == 1) ? a1.y : (ff == 2) ? a1.z : a1.w;
            int f = f4 * 4 + ff;
            const float4* wrow = (const float4*)(lw_lds + f * HIDN + u0);
            #pragma unroll
            for (int cc = 0; cc < 4; ++cc) {
                float4 wv = wrow[cc];
                acc[0][cc].x += af0 * wv.x; acc[0][cc].y += af0 * wv.y;
                acc[0][cc].z += af0 * wv.z; acc[0][cc].w += af0 * wv.w;
                acc[1][cc].x += af1 * wv.x; acc[1][cc].y += af1 * wv.y;
                acc[1][cc].z += af1 * wv.z; acc[1][cc].w += af1 * wv.w;
            }
        }
    }
    #pragma unroll
    for (int rr = 0; rr < 2; ++rr) {
        #pragma unroll
        for (int cc = 0; cc < 4; ++cc) {
            float4 ov;
            ov.x = fsig(acc[rr][cc].x);
            ov.y = fsig(acc[rr][cc].y);
            ov.z = fsig(acc[rr][cc].z);
            ov.w = fsig(acc[rr][cc].w);
            *(float4*)(out + (size_t)(r0 + rr) * HIDN + u0 + cc * 4) = ov;
        }
    }
}

// ---------------------------------------------------------------------------
extern "C" void kernel_launch(void* const* d_in, const int* in_sizes, int n_in,
                              void* d_out, int out_size, void* d_ws, size_t ws_size,
                              hipStream_t stream) {
    const float* x      = (const float*)d_in[0];
    const float* A      = (const float*)d_in[1];
    const float* conv_w = (const float*)d_in[2];
    const float* conv_b = (const float*)d_in[3];
    const float* w_ih   = (const float*)d_in[4];
    const float* w_hh   = (const float*)d_in[5];
    const float* b_ih   = (const float*)d_in[6];
    const float* b_hh   = (const float*)d_in[7];
    float* out = (float*)d_out;

    char* ws = (char*)d_ws;
    float* d_inv = (float*)ws;                                   // 64 KB
    int*   cnt   = (int*)(ws + 65536);                           // 64 KB
    int*   idx   = (int*)(ws + 131072);                          // 8 MB
    float* z4    = (float*)(ws + 131072 + 8388608);              // 1 MB
    float* lw    = (float*)(ws + 131072 + 8388608 + 1048576);    // 256 KB
    float* agg   = (float*)(ws + 131072 + 8388608 + 1048576 + 262144); // 8 MB

    hipLaunchKernelGGL(k_convz, dim3(128), dim3(512), 0, stream,
                       x, conv_w, conv_b, w_ih, b_ih, b_hh, z4);
    hipLaunchKernelGGL(k_lstm_scan, dim3(2052), dim3(512), 0, stream,
                       z4, w_hh, lw, A, d_inv, cnt, idx);
    hipLaunchKernelGGL(k_gather, dim3(2048), dim3(512), 0, stream,
                       x, d_inv, cnt, idx, agg);
    hipLaunchKernelGGL(k_outmm, dim3(256), dim3(256), 0, stream, agg, lw, out);
}

// Round 10
// 487.738 us; speedup vs baseline: 1.1533x; 1.0373x over previous
//
#include <hip/hip_runtime.h>
#include <math.h>

#define N_NODES 4096
#define HIDN 128
#define MAXNZ 128

typedef float v4f __attribute__((ext_vector_type(4)));
typedef _Float16 h2 __attribute__((ext_vector_type(2)));
typedef _Float16 h8 __attribute__((ext_vector_type(8)));

__device__ __forceinline__ float fsig(float x) { return 1.0f / (1.0f + __expf(-x)); }
__device__ __forceinline__ float ftanh_(float x) { return 1.0f - 2.0f / (__expf(2.0f * x) + 1.0f); }

// ---------------------------------------------------------------------------
// K1: conv1d + z precompute. 128 blocks x 512 thr (4 timesteps/block).
// z layout: z3[b][t:128][cell:128][gate:4]  (float4 per (t,cell))
// ---------------------------------------------------------------------------
__global__ __launch_bounds__(512) void k_convz(
        const float* __restrict__ x, const float* __restrict__ conv_w,
        const float* __restrict__ conv_b, const float* __restrict__ w_ih,
        const float* __restrict__ b_ih, const float* __restrict__ b_hh,
        float* __restrict__ z3) {
    const int cb = blockIdx.x;
    const int b = cb >> 5;
    const int t0 = (cb & 31) * 4;
    const int tsub = threadIdx.x >> 7;
    const int h = threadIdx.x & 127;
    const int t = t0 + tsub;                       // timestep 0..127
    __shared__ __align__(16) float dyn_lds[4][HIDN];
    {
        const float* xb = x + ((size_t)b * N_NODES + (N_NODES - HIDN)) * HIDN;
        const float* w = conv_w + (size_t)t * HIDN * 3;
        float a0 = conv_b[t], a1 = 0.0f, a2 = 0.0f, a3 = 0.0f;
        #pragma unroll 4
        for (int i = 0; i < HIDN; i += 4) {
            const float* xr0 = xb + (size_t)i * HIDN;
            #pragma unroll
            for (int s = 0; s < 4; ++s) {
                const float* xr = xr0 + s * HIDN;
                float w0 = w[(i + s) * 3 + 0], w1 = w[(i + s) * 3 + 1], w2 = w[(i + s) * 3 + 2];
                float left  = (h > 0)   ? xr[h - 1] : 0.0f;
                float mid   = xr[h];
                float right = (h < 127) ? xr[h + 1] : 0.0f;
                if (s == 0)      a0 += left * w0 + mid * w1 + right * w2;
                else if (s == 1) a1 += left * w0 + mid * w1 + right * w2;
                else if (s == 2) a2 += left * w0 + mid * w1 + right * w2;
                else             a3 += left * w0 + mid * w1 + right * w2;
            }
        }
        dyn_lds[tsub][h] = (a0 + a1) + (a2 + a3);
    }
    __syncthreads();
    // ---- z phase: thread = u = gate*128 + cell; 4 timesteps per thread ----
    const int u = threadIdx.x;
    const int qg = u >> 7;                         // gate
    const int m  = u & 127;                        // cell
    const float4* wr = (const float4*)(w_ih + (size_t)u * HIDN);
    float bias = b_ih[u] + b_hh[u];
    float acc0 = bias, acc1 = bias, acc2 = bias, acc3 = bias;
    #pragma unroll
    for (int half = 0; half < 2; ++half) {
        float4 wv[16];
        #pragma unroll
        for (int j = 0; j < 16; ++j) wv[j] = wr[half * 16 + j];
        const float4* d0 = (const float4*)dyn_lds[0] + half * 16;
        const float4* d1 = (const float4*)dyn_lds[1] + half * 16;
        const float4* d2 = (const float4*)dyn_lds[2] + half * 16;
        const float4* d3 = (const float4*)dyn_lds[3] + half * 16;
        #pragma unroll
        for (int j = 0; j < 16; ++j) {
            float4 wj = wv[j];
            float4 v0 = d0[j], v1 = d1[j], v2 = d2[j], v3 = d3[j];
            acc0 += wj.x * v0.x + wj.y * v0.y + wj.z * v0.z + wj.w * v0.w;
            acc1 += wj.x * v1.x + wj.y * v1.y + wj.z * v1.z + wj.w * v1.w;
            acc2 += wj.x * v2.x + wj.y * v2.y + wj.z * v2.z + wj.w * v2.w;
            acc3 += wj.x * v3.x + wj.y * v3.y + wj.z * v3.z + wj.w * v3.w;
        }
    }
    float* zb = z3 + (size_t)b * HIDN * HIDN * 4;
    zb[((size_t)(t0 + 0) * 128 + m) * 4 + qg] = acc0;
    zb[((size_t)(t0 + 1) * 128 + m) * 4 + qg] = acc1;
    zb[((size_t)(t0 + 2) * 128 + m) * 4 + qg] = acc2;
    zb[((size_t)(t0 + 3) * 128 + m) * 4 + qg] = acc3;
}

// ---------------------------------------------------------------------------
// K2 fused: blocks [0,4) = LSTM; [4,2052) = A-scan (8 rows/block).
//
// LSTM v6: thread = (cell m = t>>1, k-half = t&1), 256 working threads
// (waves 0-3); waves 4-7 help stage z then spin matching barriers.
// Per thread: all 4 gate rows over its 64-k half in f16 regs (128 VGPR),
// full-depth dots, ONE shfl_xor(1) per gate, redundant activations.
// z staged per 16-step chunk into LDS (32 KB straight copy) -> step loop
// is pure LDS+regs. __launch_bounds__(512,2) caps VGPR at 256: NO SPILL
// (R9's heuristic 68-VGPR allocation spilled the weight array into the
// serial loop).
// ---------------------------------------------------------------------------
__global__ __launch_bounds__(512, 2) void k_lstm_scan(
        const float* __restrict__ z3, const float* __restrict__ w_hh,
        float* __restrict__ lw,
        const float* __restrict__ A, float* __restrict__ d_inv,
        int* __restrict__ cnt, int* __restrict__ idx) {
    if (blockIdx.x < 4) {
        const int b = blockIdx.x;
        const int t = threadIdx.x;
        __shared__ __align__(16) h2 hbuf[2][64];       // 128 f16 h per buffer
        __shared__ __align__(16) float4 zl[16 * 128];  // 32 KB: one chunk of z
        const int m = (t < 256) ? (t >> 1) : 0;
        const int half = t & 1;
        h2 w2[4][32];
        if (t < 256) {
            #pragma unroll
            for (int g = 0; g < 4; ++g) {
                const float4* wr = (const float4*)(w_hh + ((size_t)(g * HIDN + m)) * HIDN + half * 64);
                #pragma unroll
                for (int j4 = 0; j4 < 16; ++j4) {
                    float4 wv = wr[j4];
                    w2[g][2 * j4 + 0] = h2{(_Float16)wv.x, (_Float16)wv.y};
                    w2[g][2 * j4 + 1] = h2{(_Float16)wv.z, (_Float16)wv.w};
                }
            }
        }
        float c = 0.0f;
        if (t < 64) hbuf[0][t] = h2{(_Float16)0.0f, (_Float16)0.0f};
        const float4* zsrc = (const float4*)z3 + (size_t)b * 16384;
        for (int ch = 0; ch < 8; ++ch) {
            // ---- stage chunk (all 8 waves) ----
            const float4* src = zsrc + ch * 2048;
            #pragma unroll
            for (int k = 0; k < 4; ++k)
                zl[t + 512 * k] = src[t + 512 * k];
            __syncthreads();
            if (t < 256) {
                float hist[16];
                #pragma unroll
                for (int si = 0; si < 16; ++si) {
                    const int s = ch * 16 + si;
                    // h half: 64 f16 = 8 x b128 (broadcast across lanes)
                    const h8* hp = ((const h8*)hbuf[s & 1]) + half * 8;
                    h8 H0 = hp[0], H1 = hp[1], H2 = hp[2], H3 = hp[3];
                    h8 H4 = hp[4], H5 = hp[5], H6 = hp[6], H7 = hp[7];
                    h2 hh[32];
                    #pragma unroll
                    for (int j = 0; j < 4; ++j) {
                        hh[j]      = ((const h2*)&H0)[j];
                        hh[4 + j]  = ((const h2*)&H1)[j];
                        hh[8 + j]  = ((const h2*)&H2)[j];
                        hh[12 + j] = ((const h2*)&H3)[j];
                        hh[16 + j] = ((const h2*)&H4)[j];
                        hh[20 + j] = ((const h2*)&H5)[j];
                        hh[24 + j] = ((const h2*)&H6)[j];
                        hh[28 + j] = ((const h2*)&H7)[j];
                    }
                    float4 zv = zl[si * 128 + m];      // broadcast b128
                    float a0 = 0.f, b0 = 0.f, a1 = 0.f, b1 = 0.f;
                    float a2 = 0.f, b2 = 0.f, a3 = 0.f, b3 = 0.f;
                    #pragma unroll
                    for (int j = 0; j < 16; ++j) {
                        a0 = __builtin_amdgcn_fdot2(w2[0][2 * j], hh[2 * j], a0, false);
                        b0 = __builtin_amdgcn_fdot2(w2[0][2 * j + 1], hh[2 * j + 1], b0, false);
                        a1 = __builtin_amdgcn_fdot2(w2[1][2 * j], hh[2 * j], a1, false);
                        b1 = __builtin_amdgcn_fdot2(w2[1][2 * j + 1], hh[2 * j + 1], b1, false);
                        a2 = __builtin_amdgcn_fdot2(w2[2][2 * j], hh[2 * j], a2, false);
                        b2 = __builtin_amdgcn_fdot2(w2[2][2 * j + 1], hh[2 * j + 1], b2, false);
                        a3 = __builtin_amdgcn_fdot2(w2[3][2 * j], hh[2 * j], a3, false);
                        b3 = __builtin_amdgcn_fdot2(w2[3][2 * j + 1], hh[2 * j + 1], b3, false);
                    }
                    float p0 = a0 + b0, p1 = a1 + b1, p2 = a2 + b2, p3 = a3 + b3;
                    // one butterfly level: combine the two k-halves
                    p0 += __shfl_xor(p0, 1);
                    p1 += __shfl_xor(p1, 1);
                    p2 += __shfl_xor(p2, 1);
                    p3 += __shfl_xor(p3, 1);
                    float zi = p0 + zv.x;
                    float zf = p1 + zv.y;
                    float zg = p2 + zv.z;
                    float zo = p3 + zv.w;
                    float ig = fsig(zi);
                    float fg = fsig(zf);
                    float gg = ftanh_(zg);
                    float og = fsig(zo);
                    c = fg * c + ig * gg;
                    float hn = og * ftanh_(c);
                    hist[si] = hn;
                    if (half == 0) ((_Float16*)hbuf[(s + 1) & 1])[m] = (_Float16)hn;
                    __syncthreads();
                }
                if (half == 0) {
                    float* lwb = lw + ((size_t)b * HIDN + ch * 16) * HIDN + m;
                    #pragma unroll
                    for (int si = 0; si < 16; ++si)
                        lwb[(size_t)si * HIDN] = hist[si];
                }
            } else {
                #pragma unroll
                for (int si = 0; si < 16; ++si) __syncthreads();
            }
        }
    } else {
        // ---- A-scan: 8 waves = 8 rows per block ----
        const int wid = threadIdx.x >> 6;
        const int lane = threadIdx.x & 63;
        const int r = (blockIdx.x - 4) * 8 + wid;
        const v4f* row = (const v4f*)(A + (size_t)r * N_NODES);
        __shared__ int sidx[8][MAXNZ];
        const unsigned long long below = (1ull << lane) - 1ull;
        int cbase = 0;
        v4f cur[4], nxt[4];
        #pragma unroll
        for (int j = 0; j < 4; ++j) cur[j] = row[j * 64 + lane];
#define PROC1(c, col)                                                         \
        {                                                                     \
            bool nz = ((c) != 0.0f);                                          \
            unsigned long long mm = __ballot(nz);                             \
            if (mm) {                                                         \
                if (nz) {                                                     \
                    int p_ = cbase + __popcll(mm & below);                    \
                    if (p_ < MAXNZ) sidx[wid][p_] = (col);                    \
                }                                                             \
                cbase += __popcll(mm);                                        \
            }                                                                 \
        }
        #pragma unroll
        for (int g = 0; g < 4; ++g) {
            if (g < 3) {
                #pragma unroll
                for (int j = 0; j < 4; ++j) nxt[j] = row[(g + 1) * 256 + j * 64 + lane];
            }
            #pragma unroll
            for (int j = 0; j < 4; ++j) {
                int col0 = ((g * 4 + j) * 64 + lane) * 4;
                PROC1(cur[j].x, col0 + 0);
                PROC1(cur[j].y, col0 + 1);
                PROC1(cur[j].z, col0 + 2);
                PROC1(cur[j].w, col0 + 3);
            }
            #pragma unroll
            for (int j = 0; j < 4; ++j) cur[j] = nxt[j];
        }
#undef PROC1
        int cnt_r = (cbase < MAXNZ) ? cbase : MAXNZ;
        for (int k = lane; k < cnt_r; k += 64)
            idx[r * MAXNZ + k] = sidx[wid][k];
        if (lane == 0) {
            cnt[r] = cnt_r;
            d_inv[r] = rsqrtf((float)(cbase + 1));
        }
    }
}

// ---------------------------------------------------------------------------
// K3: gather agg = D^-1/2 (A+I) D^-1/2 x. 2048 blocks x 512 thr (8 rows),
// d_inv in LDS, XCD batch pinning.
// ---------------------------------------------------------------------------
__global__ __launch_bounds__(512) void k_gather(
        const float* __restrict__ x, const float* __restrict__ d_inv,
        const int* __restrict__ cnt, const int* __restrict__ idx,
        float* __restrict__ agg) {
    const int gIdx = blockIdx.x;
    const int b = (gIdx & 7) >> 1;                 // batch pinned to XCD pair
    const int o = ((gIdx >> 3) << 1) | (gIdx & 1); // ordinal [0,512)
    const int wid = threadIdx.x >> 6;
    const int lane = threadIdx.x & 63;
    __shared__ __align__(16) float dl[N_NODES];
    {
        const float4* dsrc = (const float4*)(d_inv + (b << 12));
        float4* ddst = (float4*)dl;
        ddst[threadIdx.x] = dsrc[threadIdx.x];
        ddst[threadIdx.x + 512] = dsrc[threadIdx.x + 512];
    }
    __syncthreads();
    const int i = o * 8 + wid;                     // row within batch
    const int r = (b << 12) + i;
    const float2* xb = (const float2*)(x + (size_t)b * N_NODES * HIDN);
    const int* irow = idx + r * MAXNZ;
    const int n = cnt[r];
    float ax = 0.0f, ay = 0.0f;
    int k = 0;
    for (; k + 8 <= n; k += 8) {
        int4 j0 = *(const int4*)&irow[k];
        int4 j1 = *(const int4*)&irow[k + 4];
        float2 v0 = xb[(size_t)j0.x * 64 + lane];
        float2 v1 = xb[(size_t)j0.y * 64 + lane];
        float2 v2 = xb[(size_t)j0.z * 64 + lane];
        float2 v3 = xb[(size_t)j0.w * 64 + lane];
        float2 v4 = xb[(size_t)j1.x * 64 + lane];
        float2 v5 = xb[(size_t)j1.y * 64 + lane];
        float2 v6 = xb[(size_t)j1.z * 64 + lane];
        float2 v7 = xb[(size_t)j1.w * 64 + lane];
        float d0 = dl[j0.x], d1 = dl[j0.y], d2 = dl[j0.z], d3 = dl[j0.w];
        float d4 = dl[j1.x], d5 = dl[j1.y], d6 = dl[j1.z], d7 = dl[j1.w];
        ax += d0 * v0.x + d1 * v1.x + d2 * v2.x + d3 * v3.x
            + d4 * v4.x + d5 * v5.x + d6 * v6.x + d7 * v7.x;
        ay += d0 * v0.y + d1 * v1.y + d2 * v2.y + d3 * v3.y
            + d4 * v4.y + d5 * v5.y + d6 * v6.y + d7 * v7.y;
    }
    for (; k < n; ++k) {
        int j = irow[k];
        float dj = dl[j];
        float2 v = xb[(size_t)j * 64 + lane];
        ax += dj * v.x;
        ay += dj * v.y;
    }
    float di = dl[i];
    float2 vi = xb[(size_t)i * 64 + lane];
    float2 o2;
    o2.x = di * (ax + di * vi.x);
    o2.y = di * (ay + di * vi.y);
    ((float2*)(agg + (size_t)r * HIDN))[lane] = o2;
}

// ---------------------------------------------------------------------------
// K4: out = sigmoid(agg @ lw[b]). lw (64 KB) staged in LDS, 64 rows/block.
// ---------------------------------------------------------------------------
__global__ __launch_bounds__(256) void k_outmm(
        const float* __restrict__ agg, const float* __restrict__ lw,
        float* __restrict__ out) {
    __shared__ __align__(16) float lw_lds[HIDN * HIDN];
    const int i0 = blockIdx.x * 64;
    const int b = i0 >> 12;
    const float4* lwg = (const float4*)(lw + (size_t)b * HIDN * HIDN);
    float4* lds4 = (float4*)lw_lds;
    for (int v = threadIdx.x; v < HIDN * HIDN / 4; v += 256) lds4[v] = lwg[v];
    __syncthreads();
    const int r0 = i0 + (threadIdx.x >> 3) * 2;
    const int u0 = (threadIdx.x & 7) * 16;
    const float4* a4 = (const float4*)agg;
    float4 acc[2][4];
    #pragma unroll
    for (int rr = 0; rr < 2; ++rr)
        #pragma unroll
        for (int cc = 0; cc < 4; ++cc) acc[rr][cc] = make_float4(0.f, 0.f, 0.f, 0.f);
    for (int f4 = 0; f4 < 32; ++f4) {
        float4 a0 = a4[(size_t)r0 * 32 + f4];
        float4 a1 = a4[(size_t)(r0 + 1) * 32 + f4];
        #pragma unroll
        for (int ff = 0; ff < 4; ++ff) {
            float af0 = (ff == 0) ? a0.x : (ff == 1) ? a0.y : (ff == 2) ? a0.z : a0.w;
            float af1 = (ff == 0) ? a1.x : (ff == 1) ? a1.y : (ff == 2) ? a1.z : a1.w;
            int f = f4 * 4 + ff;
            const float4* wrow = (const float4*)(lw_lds + f * HIDN + u0);
            #pragma unroll
            for (int cc = 0; cc < 4; ++cc) {
                float4 wv = wrow[cc];
                acc[0][cc].x += af0 * wv.x; acc[0][cc].y += af0 * wv.y;
                acc[0][cc].z += af0 * wv.z; acc[0][cc].w += af0 * wv.w;
                acc[1][cc].x += af1 * wv.x; acc[1][cc].y += af1 * wv.y;
                acc[1][cc].z += af1 * wv.z; acc[1][cc].w += af1 * wv.w;
            }
        }
    }
    #pragma unroll
    for (int rr = 0; rr < 2; ++rr) {
        #pragma unroll
        for (int cc = 0; cc < 4; ++cc) {
            float4 ov;
            ov.x = fsig(acc[rr][cc].x);
            ov.y = fsig(acc[rr][cc].y);
            ov.z = fsig(acc[rr][cc].z);
            ov.w = fsig(acc[rr][cc].w);
            *(float4*)(out + (size_t)(r0 + rr) * HIDN + u0 + cc * 4) = ov;
        }
    }
}

// ---------------------------------------------------------------------------
extern "C" void kernel_launch(void* const* d_in, const int* in_sizes, int n_in,
                              void* d_out, int out_size, void* d_ws, size_t ws_size,
                              hipStream_t stream) {
    const float* x      = (const float*)d_in[0];
    const float* A      = (const float*)d_in[1];
    const float* conv_w = (const float*)d_in[2];
    const float* conv_b = (const float*)d_in[3];
    const float* w_ih   = (const float*)d_in[4];
    const float* w_hh   = (const float*)d_in[5];
    const float* b_ih   = (const float*)d_in[6];
    const float* b_hh   = (const float*)d_in[7];
    float* out = (float*)d_out;

    char* ws = (char*)d_ws;
    float* d_inv = (float*)ws;                                   // 64 KB
    int*   cnt   = (int*)(ws + 65536);                           // 64 KB
    int*   idx   = (int*)(ws + 131072);                          // 8 MB
    float* z3    = (float*)(ws + 131072 + 8388608);              // 1 MB
    float* lw    = (float*)(ws + 131072 + 8388608 + 1048576);    // 256 KB
    float* agg   = (float*)(ws + 131072 + 8388608 + 1048576 + 262144); // 8 MB

    hipLaunchKernelGGL(k_convz, dim3(128), dim3(512), 0, stream,
                       x, conv_w, conv_b, w_ih, b_ih, b_hh, z3);
    hipLaunchKernelGGL(k_lstm_scan, dim3(2052), dim3(512), 0, stream,
                       z3, w_hh, lw, A, d_inv, cnt, idx);
    hipLaunchKernelGGL(k_gather, dim3(2048), dim3(512), 0, stream,
                       x, d_inv, cnt, idx, agg);
    hipLaunchKernelGGL(k_outmm, dim3(256), dim3(256), 0, stream, agg, lw, out);
}